// Round 1
// baseline (882.190 us; speedup 1.0000x reference)
//
#include <hip/hip_runtime.h>
#include <stdint.h>

#define N_NODES 1024
#define C2v 64
#define EMB 64
#define ALPHA 0.2f
#define NEG_FILL (-1e12f)

typedef __attribute__((ext_vector_type(8))) short short8v;   // 8 bf16 in 4 VGPRs
typedef __attribute__((ext_vector_type(4))) float float4v;

static __device__ __forceinline__ short f2bf(float f) {
    unsigned u = __builtin_bit_cast(unsigned, f);
    u = (u + 0x7FFFu + ((u >> 16) & 1u)) >> 16;   // RNE
    return (short)(unsigned short)u;
}

// ---------------------------------------------------------------------------
// Kernel 1: one workgroup per row i.
//   s[i,j] = leaky_relu(x[i,j,:] @ W) . a      (bf16 MFMA, fp32 accum)
//   att[i,:] = softmax_j(s[i,:] + mask(adj[i,:]))   -> bf16 row in ws
// ---------------------------------------------------------------------------
__global__ __launch_bounds__(256) void k_att(const float* __restrict__ x,
                                             const float* __restrict__ adj,
                                             const float* __restrict__ W,
                                             const float* __restrict__ a,
                                             unsigned short* __restrict__ att) {
    __shared__ float s_lds[N_NODES];
    __shared__ float red[8];

    const int i   = blockIdx.x;
    const int tid = threadIdx.x;
    const int w   = tid >> 6;        // wave id 0..3
    const int l   = tid & 63;        // lane
    const int g   = l >> 4;          // lane group 0..3
    const int m   = l & 15;          // lane-in-group

    // W as MFMA B-fragments: wfrag[nt][ks], lane holds W[ks*32+g*8+ii][nt*16+m]
    short8v wfrag[4][2];
#pragma unroll
    for (int nt = 0; nt < 4; ++nt)
#pragma unroll
        for (int ks = 0; ks < 2; ++ks) {
            short8v v;
#pragma unroll
            for (int ii = 0; ii < 8; ++ii)
                v[ii] = f2bf(W[(ks * 32 + g * 8 + ii) * EMB + nt * 16 + m]);
            wfrag[nt][ks] = v;
        }
    float afrag[4];
#pragma unroll
    for (int nt = 0; nt < 4; ++nt) afrag[nt] = a[nt * 16 + m];

    const float* xi = x + (size_t)i * N_NODES * C2v;

    // each wave handles 16 j-rows per tile of 64
    for (int jt = 0; jt < N_NODES / 64; ++jt) {
        const int j0 = jt * 64 + w * 16;
        float4v acc[4];
#pragma unroll
        for (int nt = 0; nt < 4; ++nt) acc[nt] = (float4v)0.0f;

#pragma unroll
        for (int ks = 0; ks < 2; ++ks) {
            const float* p = xi + (size_t)(j0 + m) * C2v + ks * 32 + g * 8;
            float4v lo = *(const float4v*)p;
            float4v hi = *(const float4v*)(p + 4);
            short8v afr;
            afr[0] = f2bf(lo[0]); afr[1] = f2bf(lo[1]);
            afr[2] = f2bf(lo[2]); afr[3] = f2bf(lo[3]);
            afr[4] = f2bf(hi[0]); afr[5] = f2bf(hi[1]);
            afr[6] = f2bf(hi[2]); afr[7] = f2bf(hi[3]);
#pragma unroll
            for (int nt = 0; nt < 4; ++nt)
                acc[nt] = __builtin_amdgcn_mfma_f32_16x16x32_bf16(
                    afr, wfrag[nt][ks], acc[nt], 0, 0, 0);
        }
        // s[j] = sum_e lrelu(wx[j,e]) * a[e]; C/D layout: row=g*4+r, col=m
#pragma unroll
        for (int r = 0; r < 4; ++r) {
            float v = 0.f;
#pragma unroll
            for (int nt = 0; nt < 4; ++nt) {
                float t = acc[nt][r];
                t = (t > 0.f) ? t : (ALPHA * t);
                v += t * afrag[nt];
            }
            v += __shfl_xor(v, 1);
            v += __shfl_xor(v, 2);
            v += __shfl_xor(v, 4);
            v += __shfl_xor(v, 8);
            if (m == 0) s_lds[j0 + g * 4 + r] = v;
        }
    }
    __syncthreads();

    // masked softmax over the 1024 entries
    const float* adjrow = adj + (size_t)i * N_NODES;
    float sc[4];
    float lmax = -3.4e38f;
#pragma unroll
    for (int q = 0; q < 4; ++q) {
        int j = tid + q * 256;
        float v = s_lds[j] + (adjrow[j] > 0.f ? 0.f : NEG_FILL);
        sc[q] = v;
        lmax = fmaxf(lmax, v);
    }
#pragma unroll
    for (int d = 1; d < 64; d <<= 1) lmax = fmaxf(lmax, __shfl_xor(lmax, d));
    if (l == 0) red[w] = lmax;
    __syncthreads();
    const float M = fmaxf(fmaxf(red[0], red[1]), fmaxf(red[2], red[3]));

    float ex[4];
    float lsum = 0.f;
#pragma unroll
    for (int q = 0; q < 4; ++q) {
        ex[q] = __expf(sc[q] - M);
        lsum += ex[q];
    }
#pragma unroll
    for (int d = 1; d < 64; d <<= 1) lsum += __shfl_xor(lsum, d);
    __syncthreads();
    if (l == 0) red[w] = lsum;
    __syncthreads();
    const float S = red[0] + red[1] + red[2] + red[3];
    const float inv = 1.0f / S;

    unsigned short* arow = att + (size_t)i * N_NODES;
#pragma unroll
    for (int q = 0; q < 4; ++q) {
        int j = tid + q * 256;
        arow[j] = (unsigned short)f2bf(ex[q] * inv);
    }
}

// ---------------------------------------------------------------------------
// Kernel 2: out[b] = (att @ x[b]) @ W + bias
// grid 4096 = (batch b, i-tile of 256); XCD-swizzled so a batch's 4 tiles
// share one XCD's L2 (x[b] = 256 KB reused 4x).
// ---------------------------------------------------------------------------
__global__ __launch_bounds__(256) void k_out(const float* __restrict__ x,
                                             const unsigned short* __restrict__ att,
                                             const float* __restrict__ W,
                                             const float* __restrict__ bias,
                                             float* __restrict__ out) {
    __shared__ __attribute__((aligned(16))) short tmp_lds[256][72];

    const int hw = blockIdx.x;
    const int L  = (hw & 7) * 512 + (hw >> 3);   // bijective XCD swizzle (4096 % 8 == 0)
    const int b  = L >> 2;
    const int it = L & 3;

    const int tid = threadIdx.x;
    const int w   = tid >> 6;
    const int l   = tid & 63;
    const int g   = l >> 4;
    const int m   = l & 15;

    float4v acc[4][4];
#pragma unroll
    for (int mt = 0; mt < 4; ++mt)
#pragma unroll
        for (int nt = 0; nt < 4; ++nt) acc[mt][nt] = (float4v)0.0f;

    const float* xb = x + (size_t)b * N_NODES * C2v;

    for (int kt = 0; kt < 16; ++kt) {
        const int j0 = kt * 64;

        // A fragments: att rows (already bf16 in ws), 16B contiguous per lane
        short8v afr[4][2];
#pragma unroll
        for (int mt = 0; mt < 4; ++mt)
#pragma unroll
            for (int ks = 0; ks < 2; ++ks) {
                const int row = it * 256 + w * 64 + mt * 16 + m;
                afr[mt][ks] = *(const short8v*)&att[(size_t)row * N_NODES + j0 + ks * 32 + g * 8];
            }

        // B fragments: x[b][j][c] column gathers (L1/L2-hot), convert to bf16
        short8v bfr[4][2];
#pragma unroll
        for (int nt = 0; nt < 4; ++nt)
#pragma unroll
            for (int ks = 0; ks < 2; ++ks) {
                short8v v;
#pragma unroll
                for (int ii = 0; ii < 8; ++ii) {
                    const int j = j0 + ks * 32 + g * 8 + ii;
                    v[ii] = f2bf(xb[(size_t)j * C2v + nt * 16 + m]);
                }
                bfr[nt][ks] = v;
            }

#pragma unroll
        for (int mt = 0; mt < 4; ++mt)
#pragma unroll
            for (int nt = 0; nt < 4; ++nt)
#pragma unroll
                for (int ks = 0; ks < 2; ++ks)
                    acc[mt][nt] = __builtin_amdgcn_mfma_f32_16x16x32_bf16(
                        afr[mt][ks], bfr[nt][ks], acc[mt][nt], 0, 0, 0);
    }

    // tmp = att@x[b] -> LDS bf16 (layout change for second GEMM A operand)
#pragma unroll
    for (int mt = 0; mt < 4; ++mt)
#pragma unroll
        for (int nt = 0; nt < 4; ++nt)
#pragma unroll
            for (int r = 0; r < 4; ++r)
                tmp_lds[w * 64 + mt * 16 + g * 4 + r][nt * 16 + m] = f2bf(acc[mt][nt][r]);
    __syncthreads();

    // W fragments (loaded late to keep main-loop VGPR pressure down) + bias
    short8v wfrag[4][2];
#pragma unroll
    for (int nt = 0; nt < 4; ++nt)
#pragma unroll
        for (int ks = 0; ks < 2; ++ks) {
            short8v v;
#pragma unroll
            for (int ii = 0; ii < 8; ++ii)
                v[ii] = f2bf(W[(ks * 32 + g * 8 + ii) * EMB + nt * 16 + m]);
            wfrag[nt][ks] = v;
        }
    float bfrag[4];
#pragma unroll
    for (int nt = 0; nt < 4; ++nt) bfrag[nt] = bias[nt * 16 + m];

    // out = tmp @ W
    float4v acc2[4][4];
#pragma unroll
    for (int mt = 0; mt < 4; ++mt)
#pragma unroll
        for (int nt = 0; nt < 4; ++nt) acc2[mt][nt] = (float4v)0.0f;

#pragma unroll
    for (int mt = 0; mt < 4; ++mt)
#pragma unroll
        for (int ks = 0; ks < 2; ++ks) {
            const short8v a2 = *(const short8v*)&tmp_lds[w * 64 + mt * 16 + m][ks * 32 + g * 8];
#pragma unroll
            for (int nt = 0; nt < 4; ++nt)
                acc2[mt][nt] = __builtin_amdgcn_mfma_f32_16x16x32_bf16(
                    a2, wfrag[nt][ks], acc2[mt][nt], 0, 0, 0);
        }

#pragma unroll
    for (int mt = 0; mt < 4; ++mt)
#pragma unroll
        for (int nt = 0; nt < 4; ++nt)
#pragma unroll
            for (int r = 0; r < 4; ++r) {
                const int i = it * 256 + w * 64 + mt * 16 + g * 4 + r;
                const int e = nt * 16 + m;
                out[((size_t)b * N_NODES + i) * EMB + e] = acc2[mt][nt][r] + bfrag[nt];
            }
}

extern "C" void kernel_launch(void* const* d_in, const int* in_sizes, int n_in,
                              void* d_out, int out_size, void* d_ws, size_t ws_size,
                              hipStream_t stream) {
    const float* x    = (const float*)d_in[0];   // [1024,1024,64]
    const float* adj  = (const float*)d_in[1];   // [1024,1024]
    const float* W    = (const float*)d_in[2];   // [64,64]
    const float* a    = (const float*)d_in[3];   // [64]
    const float* bias = (const float*)d_in[4];   // [64]
    float* out = (float*)d_out;
    unsigned short* att = (unsigned short*)d_ws; // 1024*1024 bf16 = 2 MB

    k_att<<<N_NODES, 256, 0, stream>>>(x, adj, W, a, att);
    k_out<<<4096, 256, 0, stream>>>(x, att, W, bias, out);
}